// Round 7
// baseline (246.643 us; speedup 1.0000x reference)
//
#include <hip/hip_runtime.h>

#define CAP 64
#define OVF_MAX 8192

// ---------------- kernels ----------------

// Prelude: zero cur/ovfc; 16 blocks compute Wc = W2@Wout (row-major); 1 block bc.
__global__ void k_pre(int* __restrict__ cur, int* __restrict__ ovfc, int N,
                      const float* __restrict__ W2, const float* __restrict__ Wout,
                      const float* __restrict__ b2, const float* __restrict__ bout,
                      float* __restrict__ Wc, float* __restrict__ bc, int zb) {
    int tid = threadIdx.x;
    int bid = blockIdx.x;
    if (bid < zb) {
        int n = bid * 256 + tid;
        if (n < N) cur[n] = 0;
        if (n == N) *ovfc = 0;
        return;
    }
    int wb = bid - zb;
    if (wb < 16) {
        int idx = wb * 256 + tid;
        int j = idx >> 6, i = idx & 63;
        float s = 0.0f;
        #pragma unroll 8
        for (int m = 0; m < 64; ++m)
            s = fmaf(W2[i * 64 + m], Wout[m * 64 + j], s);
        Wc[i * 64 + j] = s;
    } else if (tid < 64) {
        float s = bout[tid];
        for (int k = 0; k < 64; ++k)
            s = fmaf(b2[k], Wout[k * 64 + tid], s);
        bc[tid] = s;
    }
}

// Fat kernel, roles interleaved by parity:
//  even blocks: bucket edges by dst (one atomic per edge)
//  odd  blocks: xa = mean over T of x (pure streaming, no GEMM)
__global__ __launch_bounds__(256) void k_scatmean(
        const int* __restrict__ ei, const float* __restrict__ ea,
        int* __restrict__ cur, int2* __restrict__ eb,
        int* __restrict__ ovf_cnt, int4* __restrict__ ovf,
        int E, int scatterBlocks,
        const float* __restrict__ x, float* __restrict__ xa, int N,
        int meanBlocks) {
    int tid = threadIdx.x;
    int bid = (int)blockIdx.x;
    int nmin = scatterBlocks < meanBlocks ? scatterBlocks : meanBlocks;
    int isScat, rid;
    if (bid < 2 * nmin) { isScat = !(bid & 1); rid = bid >> 1; }
    else { isScat = (scatterBlocks > meanBlocks); rid = bid - 2 * nmin + nmin; }

    if (isScat) {
        int e = rid * 256 + tid;
        if (e < E) {
            int s = ei[e];
            int d = ei[E + e];
            float w = ea[(size_t)e * 16 + 15];
            int p = atomicAdd(cur + d, 1);
            if (p < CAP) {
                eb[(size_t)d * CAP + p] = make_int2(s, __float_as_int(w));
            } else {
                int q = atomicAdd(ovf_cnt, 1);
                if (q < OVF_MAX) ovf[q] = make_int4(s, d, __float_as_int(w), 0);
            }
        }
        return;
    }
    int w = tid >> 6, l = tid & 63;
    for (int it = 0; it < 4; ++it) {
        int n = rid * 16 + it * 4 + w;        // wave-uniform
        if (n >= N) continue;
        // coalesced 1KB reads; float4 #(k*64+l) lies in channel c = k*16 + (l>>2)
        const float4* xp = (const float4*)(x + (size_t)n * 1024);
        float4 v0 = xp[l], v1 = xp[64 + l], v2 = xp[128 + l], v3 = xp[192 + l];
        float s0 = (v0.x + v0.y) + (v0.z + v0.w);
        float s1 = (v1.x + v1.y) + (v1.z + v1.w);
        float s2 = (v2.x + v2.y) + (v2.z + v2.w);
        float s3 = (v3.x + v3.y) + (v3.z + v3.w);
        s0 += __shfl_xor(s0, 1); s0 += __shfl_xor(s0, 2);
        s1 += __shfl_xor(s1, 1); s1 += __shfl_xor(s1, 2);
        s2 += __shfl_xor(s2, 1); s2 += __shfl_xor(s2, 2);
        s3 += __shfl_xor(s3, 1); s3 += __shfl_xor(s3, 2);
        // lane l wants channel l = (l>>4)*16 + (l&15): held as s_{l>>4} on quad (l&15)
        int srcl = (l & 15) << 2;
        float t0 = __shfl(s0, srcl), t1 = __shfl(s1, srcl);
        float t2 = __shfl(s2, srcl), t3 = __shfl(s3, srcl);
        int k = l >> 4;
        float v = (k == 0) ? t0 : (k == 1) ? t1 : (k == 2) ? t2 : t3;
        xa[(size_t)n * 64 + l] = v * 0.0625f;
    }
}

// dinv[n] = 1/sqrt(1 + sum of ew over node n's bucket). 4 lanes per node.
__global__ void k_dinvb(const int* __restrict__ cur, const int2* __restrict__ eb,
                        const int* __restrict__ ovf_cnt, const int4* __restrict__ ovf,
                        float* __restrict__ dinv, int N) {
    int tid = threadIdx.x;
    int n = blockIdx.x * 64 + (tid >> 2);
    int j = tid & 3;
    if (n >= N) return;
    int mfull = cur[n];
    int m = mfull > CAP ? CAP : mfull;
    float s = 0.0f;
    for (int i = j; i < m; i += 4) s += __int_as_float(eb[(size_t)n * CAP + i].y);
    s += __shfl_xor(s, 1);
    s += __shfl_xor(s, 2);
    if (j == 0) {
        if (mfull > CAP) {
            int oc = *ovf_cnt; if (oc > OVF_MAX) oc = OVF_MAX;
            for (int k = 0; k < oc; ++k) {
                int4 o = ovf[k];
                if (o.y == n) s += __int_as_float(o.z);
            }
        }
        dinv[n] = 1.0f / sqrtf(s + 1.0f);
    }
}

// Fused GCN aggregation + register-resident GEMM. One wave per node, lane = channel.
// r[c] = dv*( Σ_e in[src][c]*(ew*dinv[src]) + in[n][c]*dv )
// out[n][c] = [relu]( bias[c] + Σ_i r[i]*W[i][c] )   (W column c lives in VGPRs)
template <int RELU>
__global__ __launch_bounds__(256) void k_aggW(const float* __restrict__ in,
                                              const float* __restrict__ W,
                                              const float* __restrict__ bias,
                                              const float* __restrict__ dinv,
                                              const int* __restrict__ cur,
                                              const int2* __restrict__ eb,
                                              const int* __restrict__ ovf_cnt,
                                              const int4* __restrict__ ovf,
                                              float* __restrict__ out, int N) {
    __shared__ float rbuf[4 * 64];
    int tid = threadIdx.x;
    int w = tid >> 6, c = tid & 63;
    float wreg[64];
    #pragma unroll
    for (int i = 0; i < 64; ++i) wreg[i] = W[i * 64 + c];   // coalesced, L2-hot
    float bias_c = bias[c];
    float* rw = rbuf + w * 64;
    for (int it = 0; it < 4; ++it) {
        int n = blockIdx.x * 16 + it * 4 + w;   // wave-uniform
        if (n >= N) continue;
        float dv = dinv[n];
        float selfv = in[(size_t)n * 64 + c];
        float a0 = 0.f, a1 = 0.f, a2 = 0.f, a3 = 0.f;
        const int2* bkt = eb + (size_t)n * CAP;
        int mfull = cur[n];
        int m = mfull > CAP ? CAP : mfull;
        int i = 0;
        for (; i + 8 <= m; i += 8) {
            int2 e0 = bkt[i + 0], e1 = bkt[i + 1], e2 = bkt[i + 2], e3 = bkt[i + 3];
            int2 e4 = bkt[i + 4], e5 = bkt[i + 5], e6 = bkt[i + 6], e7 = bkt[i + 7];
            float d0 = dinv[e0.x], d1 = dinv[e1.x], d2 = dinv[e2.x], d3 = dinv[e3.x];
            float d4 = dinv[e4.x], d5 = dinv[e5.x], d6 = dinv[e6.x], d7 = dinv[e7.x];
            float v0 = in[(size_t)e0.x * 64 + c], v1 = in[(size_t)e1.x * 64 + c];
            float v2 = in[(size_t)e2.x * 64 + c], v3 = in[(size_t)e3.x * 64 + c];
            float v4 = in[(size_t)e4.x * 64 + c], v5 = in[(size_t)e5.x * 64 + c];
            float v6 = in[(size_t)e6.x * 64 + c], v7 = in[(size_t)e7.x * 64 + c];
            a0 = fmaf(v0, __int_as_float(e0.y) * d0, a0);
            a1 = fmaf(v1, __int_as_float(e1.y) * d1, a1);
            a2 = fmaf(v2, __int_as_float(e2.y) * d2, a2);
            a3 = fmaf(v3, __int_as_float(e3.y) * d3, a3);
            a0 = fmaf(v4, __int_as_float(e4.y) * d4, a0);
            a1 = fmaf(v5, __int_as_float(e5.y) * d5, a1);
            a2 = fmaf(v6, __int_as_float(e6.y) * d6, a2);
            a3 = fmaf(v7, __int_as_float(e7.y) * d7, a3);
        }
        for (; i < m; ++i) {
            int2 e = bkt[i];
            a0 = fmaf(in[(size_t)e.x * 64 + c], __int_as_float(e.y) * dinv[e.x], a0);
        }
        if (mfull > CAP) {                      // wave-uniform, ~never taken
            int oc = *ovf_cnt; if (oc > OVF_MAX) oc = OVF_MAX;
            for (int k = 0; k < oc; ++k) {
                int4 o = ovf[k];
                if (o.y == n)
                    a0 = fmaf(in[(size_t)o.x * 64 + c], __int_as_float(o.z) * dinv[o.x], a0);
            }
        }
        float r = dv * (((a0 + a1) + (a2 + a3)) + selfv * dv);
        // GEMM: stage r in LDS, broadcast-read back; W from VGPRs.
        rw[c] = r;
        float acc = bias_c;
        const float4* rb4 = (const float4*)rw;
        #pragma unroll
        for (int q = 0; q < 16; ++q) {
            float4 rv = rb4[q];                 // broadcast (same addr all lanes)
            acc = fmaf(rv.x, wreg[4 * q + 0], acc);
            acc = fmaf(rv.y, wreg[4 * q + 1], acc);
            acc = fmaf(rv.z, wreg[4 * q + 2], acc);
            acc = fmaf(rv.w, wreg[4 * q + 3], acc);
        }
        if (RELU) acc = fmaxf(acc, 0.0f);
        out[(size_t)n * 64 + c] = acc;
    }
}

// ---------------- launcher ----------------

extern "C" void kernel_launch(void* const* d_in, const int* in_sizes, int n_in,
                              void* d_out, int out_size, void* d_ws, size_t ws_size,
                              hipStream_t stream) {
    const float* x    = (const float*)d_in[0];
    const int*   ei   = (const int*)d_in[1];
    const float* ea   = (const float*)d_in[2];
    const float* W1   = (const float*)d_in[3];
    const float* b1   = (const float*)d_in[4];
    const float* W2   = (const float*)d_in[5];
    const float* b2   = (const float*)d_in[6];
    const float* Wout = (const float*)d_in[7];
    const float* bout = (const float*)d_in[8];
    float* out = (float*)d_out;

    const int N = in_sizes[0] / (64 * 16);   // 50000
    const int E = in_sizes[1] / 2;           // 800000

    // workspace layout
    char* wsb = (char*)d_ws;
    int4*  ovf  = (int4*)wsb;                       // 128KB
    int2*  eb   = (int2*)(wsb + OVF_MAX * 16);      // N*CAP*8B
    float* XA   = (float*)(wsb + OVF_MAX * 16 + (size_t)N * CAP * 8);
    size_t NC = (size_t)N * 64;
    float* Z    = XA + NC;
    int*   cur  = (int*)(Z + NC);
    float* dinv = (float*)(cur + N);
    int*   ovfc = (int*)(dinv + N);
    float* Wc   = (float*)(ovfc + 4);
    float* bc   = Wc + 4096;

    dim3 b256(256);
    int meanBlocks    = (N + 15) / 16;       // 3125
    int scatterBlocks = (E + 255) / 256;     // 3125
    int zb = (N + 256) / 256;                // covers n == N too

    hipLaunchKernelGGL(k_pre, dim3(zb + 17), b256, 0, stream,
                       cur, ovfc, N, W2, Wout, b2, bout, Wc, bc, zb);
    hipLaunchKernelGGL(k_scatmean, dim3(scatterBlocks + meanBlocks), b256, 0, stream,
                       ei, ea, cur, eb, ovfc, ovf, E, scatterBlocks, x, XA, N, meanBlocks);
    hipLaunchKernelGGL(k_dinvb, dim3((N + 63) / 64), b256, 0, stream,
                       cur, eb, ovfc, ovf, dinv, N);
    // layer 1: z = relu(agg(xa) @ W1 + b1)
    hipLaunchKernelGGL((k_aggW<1>), dim3(meanBlocks), b256, 0, stream,
                       XA, W1, b1, dinv, cur, eb, ovfc, ovf, Z, N);
    // layer 2+out: out = agg(z) @ Wc + bc
    hipLaunchKernelGGL((k_aggW<0>), dim3(meanBlocks), b256, 0, stream,
                       Z, Wc, bc, dinv, cur, eb, ovfc, ovf, out, N);
}